// Round 13
// baseline (159.064 us; speedup 1.0000x reference)
//
#include <hip/hip_runtime.h>
#include <float.h>
#include <math.h>

#define Bn 8
#define Cn 256
#define Hn 160
#define Wn 160
#define HWn (Hn * Wn)          // 25600
#define NPIX (Bn * HWn)        // 204800
#define PPB 128                // pixels per block
#define BLKS (NPIX / PPB)      // 1600 (HWn % 128 == 0 -> no batch straddle)

typedef float v4f __attribute__((ext_vector_type(4)));

// Fused flag-pipelined kernel, v2 (occupancy-doubled vs R10):
//  - 1600 blocks x 256 threads, 128 px/block -> 6.25 blocks/CU resident
//    (R10's 800-block version was grid-starved at 31% occupancy, 2.3 TB/s).
//  - __launch_bounds__(256,8) caps VGPR<=64 so ALL 1600 blocks are
//    co-resident (2048-block device capacity) -> spin-wait is deadlock-safe.
//  phase 1: block reduces its 128 px over 256 channels (8 x 32-ch sets,
//           512 B/wave segments -- R11/R12-proven shape); partials combined
//           in LDS; desc written with agent-scope stores; release flag[bid].
//  wait:    acquire-spin on exactly the halo-producer blocks (<=11, in-batch).
//  phase 2a: coalesced agent-load of desc halo rows into LDS; conv7+conv3+
//           sigmoid by 128 threads -> w_lds.
//  phase 2b: out = x*w channel sweep; x re-read is L3-hot (R7/R9/R10:
//           FETCH == one x read); NT stores keep out from evicting x.
__global__ __launch_bounds__(256, 8) void k_fused(const float* __restrict__ x,
                                                  const float* __restrict__ w7,
                                                  const float* __restrict__ w3,
                                                  const float* __restrict__ alphap,
                                                  float* __restrict__ avgp,
                                                  float* __restrict__ maxp,
                                                  int* __restrict__ flags,
                                                  float* __restrict__ out) {
    const int tid  = threadIdx.x;
    const int lane = tid & 63;
    const int wv   = tid >> 6;
    const int bid  = blockIdx.x;
    const int base = bid * PPB;          // first pixel of this block
    const int b    = base / HWn;
    const int hwb  = base - b * HWn;
    const int g    = lane & 31;          // f4 group within 128 px (0..31)
    const int cs   = lane >> 5;          // channel sub-select within wave
    const size_t off0 = (size_t)b * Cn * HWn + hwb + (g << 2);

    // Aliased LDS: phase 1 partials (8 KB) then desc halo tile (<=10 KB).
    __shared__ __align__(16) float shmem[2880];
    __shared__ float w_lds[PPB];
    float4* ps = reinterpret_cast<float4*>(shmem);   // [8][32] sum partials
    float4* pm = ps + 256;                           // [8][32] max partials

    // ---------------- Phase 1: per-pixel channel mean + max ----------------
    {
        const float* xp = x + off0;
        const int c0 = (wv << 6) + (cs << 5);        // 32 channels per set
        float4 s = make_float4(0.f, 0.f, 0.f, 0.f);
        float4 m = make_float4(-FLT_MAX, -FLT_MAX, -FLT_MAX, -FLT_MAX);
        #pragma unroll 8
        for (int k = 0; k < 32; ++k) {
            const float4 v = *reinterpret_cast<const float4*>(xp + (size_t)(c0 + k) * HWn);
            s.x += v.x; s.y += v.y; s.z += v.z; s.w += v.w;
            m.x = fmaxf(m.x, v.x); m.y = fmaxf(m.y, v.y);
            m.z = fmaxf(m.z, v.z); m.w = fmaxf(m.w, v.w);
        }
        const int set = (wv << 1) + cs;              // 0..7
        ps[set * 32 + g] = s;
        pm[set * 32 + g] = m;
        __syncthreads();

        if (tid < 64) {
            const int gg = tid & 31;
            if (tid < 32) {
                float4 a0 = ps[gg], a1 = ps[32 + gg], a2 = ps[64 + gg], a3 = ps[96 + gg];
                float4 a4 = ps[128 + gg], a5 = ps[160 + gg], a6 = ps[192 + gg], a7 = ps[224 + gg];
                const float inv = 1.0f / (float)Cn;
                float4 av;
                av.x = (((a0.x + a1.x) + (a2.x + a3.x)) + ((a4.x + a5.x) + (a6.x + a7.x))) * inv;
                av.y = (((a0.y + a1.y) + (a2.y + a3.y)) + ((a4.y + a5.y) + (a6.y + a7.y))) * inv;
                av.z = (((a0.z + a1.z) + (a2.z + a3.z)) + ((a4.z + a5.z) + (a6.z + a7.z))) * inv;
                av.w = (((a0.w + a1.w) + (a2.w + a3.w)) + ((a4.w + a5.w) + (a6.w + a7.w))) * inv;
                const int p = base + (gg << 2);
                __hip_atomic_store(&avgp[p+0], av.x, __ATOMIC_RELAXED, __HIP_MEMORY_SCOPE_AGENT);
                __hip_atomic_store(&avgp[p+1], av.y, __ATOMIC_RELAXED, __HIP_MEMORY_SCOPE_AGENT);
                __hip_atomic_store(&avgp[p+2], av.z, __ATOMIC_RELAXED, __HIP_MEMORY_SCOPE_AGENT);
                __hip_atomic_store(&avgp[p+3], av.w, __ATOMIC_RELAXED, __HIP_MEMORY_SCOPE_AGENT);
            } else {
                float4 m0 = pm[gg], m1 = pm[32 + gg], m2 = pm[64 + gg], m3 = pm[96 + gg];
                float4 m4 = pm[128 + gg], m5 = pm[160 + gg], m6 = pm[192 + gg], m7 = pm[224 + gg];
                float4 mx;
                mx.x = fmaxf(fmaxf(fmaxf(m0.x, m1.x), fmaxf(m2.x, m3.x)),
                             fmaxf(fmaxf(m4.x, m5.x), fmaxf(m6.x, m7.x)));
                mx.y = fmaxf(fmaxf(fmaxf(m0.y, m1.y), fmaxf(m2.y, m3.y)),
                             fmaxf(fmaxf(m4.y, m5.y), fmaxf(m6.y, m7.y)));
                mx.z = fmaxf(fmaxf(fmaxf(m0.z, m1.z), fmaxf(m2.z, m3.z)),
                             fmaxf(fmaxf(m4.z, m5.z), fmaxf(m6.z, m7.z)));
                mx.w = fmaxf(fmaxf(fmaxf(m0.w, m1.w), fmaxf(m2.w, m3.w)),
                             fmaxf(fmaxf(m4.w, m5.w), fmaxf(m6.w, m7.w)));
                const int p = base + (gg << 2);
                __hip_atomic_store(&maxp[p+0], mx.x, __ATOMIC_RELAXED, __HIP_MEMORY_SCOPE_AGENT);
                __hip_atomic_store(&maxp[p+1], mx.y, __ATOMIC_RELAXED, __HIP_MEMORY_SCOPE_AGENT);
                __hip_atomic_store(&maxp[p+2], mx.z, __ATOMIC_RELAXED, __HIP_MEMORY_SCOPE_AGENT);
                __hip_atomic_store(&maxp[p+3], mx.w, __ATOMIC_RELAXED, __HIP_MEMORY_SCOPE_AGENT);
            }
        }
    }

    // Desc stores retired (vmcnt drained at barrier) -> release flag.
    __syncthreads();
    if (tid == 0) {
        __hip_atomic_store(&flags[bid], 1, __ATOMIC_RELEASE, __HIP_MEMORY_SCOPE_AGENT);
    }

    // Halo rows and the exact producer-block range (within this batch).
    const int r0 = hwb / Wn;
    const int rl = (hwb + PPB - 1) / Wn;
    const int rs = (r0 - 3 < 0) ? 0 : r0 - 3;
    const int re = (rl + 3 > Hn - 1) ? Hn - 1 : rl + 3;
    const int nrows = re - rs + 1;                   // <= 8
    const int prow  = nrows * Wn;
    const int first = (b * HWn + rs * Wn) / PPB;
    const int last  = (b * HWn + (re + 1) * Wn - 1) / PPB;
    if (tid <= last - first) {
        while (__hip_atomic_load(&flags[first + tid], __ATOMIC_ACQUIRE, __HIP_MEMORY_SCOPE_AGENT) == 0) {
            __builtin_amdgcn_s_sleep(2);
        }
    }
    __syncthreads();

    // ---- Phase 2a: stage desc halo into LDS (coalesced agent loads) ----
    {
        const size_t bofs = (size_t)b * HWn + rs * Wn;
        const float* srcA = avgp + bofs;
        const float* srcM = maxp + bofs;
        const int total = 2 * prow;                  // <= 2560
        for (int idx = tid; idx < total; idx += 256) {
            const int  inA = idx < prow;
            const int  o   = inA ? idx : idx - prow;
            const float* s = inA ? srcA : srcM;
            shmem[idx] = __hip_atomic_load(&s[o], __ATOMIC_RELAXED, __HIP_MEMORY_SCOPE_AGENT);
        }
    }
    __syncthreads();

    // ---- conv7 + conv3 -> sigmoid -> w_lds (taps from LDS) ----
    if (tid < PPB) {
        const int hw = hwb + tid;
        const int h  = hw / Wn;
        const int w  = hw - h * Wn;

        float a7 = 0.f;
        #pragma unroll
        for (int kh = 0; kh < 7; ++kh) {
            const int hh = h + kh - 3;
            if (hh < 0 || hh >= Hn) continue;
            const float* arow = &shmem[(hh - rs) * Wn];
            const float* mrow = arow + prow;
            #pragma unroll
            for (int kw = 0; kw < 7; ++kw) {
                const int ww = w + kw - 3;
                if (ww < 0 || ww >= Wn) continue;
                a7 = fmaf(arow[ww], w7[kh * 7 + kw], a7);
                a7 = fmaf(mrow[ww], w7[49 + kh * 7 + kw], a7);
            }
        }

        float a3 = 0.f;
        #pragma unroll
        for (int kh = 0; kh < 3; ++kh) {
            const int hh = h + kh - 1;
            if (hh < 0 || hh >= Hn) continue;
            const float* arow = &shmem[(hh - rs) * Wn];
            const float* mrow = arow + prow;
            #pragma unroll
            for (int kw = 0; kw < 3; ++kw) {
                const int ww = w + kw - 1;
                if (ww < 0 || ww >= Wn) continue;
                a3 = fmaf(arow[ww], w3[kh * 3 + kw], a3);
                a3 = fmaf(mrow[ww], w3[9 + kh * 3 + kw], a3);
            }
        }

        const float alpha = *alphap;
        const float z = alpha * a7 + (1.0f - alpha) * a3;
        w_lds[tid] = 1.0f / (1.0f + expf(-z));
    }
    __syncthreads();

    // ---------------- Phase 2b: out = x * w (plain loads, NT stores) -------
    {
        const int cset = tid >> 5;                   // 0..7, 32 channels each
        const float4 wf = reinterpret_cast<const float4*>(w_lds)[g];
        const v4f wvf = { wf.x, wf.y, wf.z, wf.w };
        const v4f* __restrict__ xin = reinterpret_cast<const v4f*>(x + off0);
        v4f* __restrict__ oout = reinterpret_cast<v4f*>(out + off0);
        const int c0 = cset << 5;

        #pragma unroll 8
        for (int k = 0; k < 32; ++k) {
            const size_t idx = (size_t)(c0 + k) * (HWn / 4);
            const v4f xv = xin[idx];
            __builtin_nontemporal_store(xv * wvf, oout + idx);
        }
    }
}

extern "C" void kernel_launch(void* const* d_in, const int* in_sizes, int n_in,
                              void* d_out, int out_size, void* d_ws, size_t ws_size,
                              hipStream_t stream) {
    const float* x      = (const float*)d_in[0];
    const float* w7     = (const float*)d_in[1];
    const float* w3     = (const float*)d_in[2];
    const float* alphap = (const float*)d_in[3];
    float* out = (float*)d_out;

    float* avgp = (float*)d_ws;          // NPIX floats
    float* maxp = avgp + NPIX;           // NPIX floats
    int*   flags = (int*)(maxp + NPIX);  // BLKS ints (zeroed every call)

    hipMemsetAsync(flags, 0, BLKS * sizeof(int), stream);
    k_fused<<<BLKS, 256, 0, stream>>>(x, w7, w3, alphap, avgp, maxp, flags, out);
}